// Round 7
// baseline (23588.165 us; speedup 1.0000x reference)
//
#include <hip/hip_runtime.h>
#include <hip/hip_bf16.h>

#define N_NODES 50000
#define R_REL   8
#define E_EDGES 200000
#define ETOT    (E_EDGES + N_NODES)   // 250000 per relation (incl self loops)
#define D_INP   128
#define HIDC    128
#define NH      4
#define F1      (NH*HIDC)             // 512
#define F2      256
#define LN_EPS  1e-5f
#define SM_EPS  1e-16f

typedef unsigned short u16;
typedef __bf16 bf16x4 __attribute__((ext_vector_type(4)));
typedef float  f32x4  __attribute__((ext_vector_type(4)));

__device__ __forceinline__ float bf2f(u16 u){
  union { unsigned int i; float f; } v; v.i = ((unsigned int)u) << 16; return v.f;
}
__device__ __forceinline__ u16 f2bf(float f){
  union { float f; unsigned int i; } v; v.f = f;
  unsigned int r = v.i + 0x7FFFu + ((v.i >> 16) & 1u);
  return (u16)(r >> 16);
}

// ---------------------------------------------------------------- VALU GEMM
// C[M,Nn] = A[M,K] * W(f32)[K,Nn]; A bf16 (AF32=false) or f32 (AF32=true).
// f32 accumulate; bf16 out. 64x64 tile, 256 threads, 4x4 per thread.
template<bool AF32>
__global__ __launch_bounds__(256)
void k_vgemm(const u16* __restrict__ Ab, const float* __restrict__ Af,
             const float* __restrict__ W, u16* __restrict__ C, int M, int K, int Nn)
{
  __shared__ float As[16][64];   // [k][m]
  __shared__ float Bs[16][64];   // [k][n]
  const int t = threadIdx.x;
  const long m0 = (long)blockIdx.y * 64, n0 = (long)blockIdx.x * 64;
  const int ty = t >> 4, tx = t & 15;

  float acc[4][4];
#pragma unroll
  for (int i=0;i<4;i++)
#pragma unroll
    for (int j=0;j<4;j++) acc[i][j] = 0.f;

  for (int k0 = 0; k0 < K; k0 += 16) {
    __syncthreads();
    {
      int row = t >> 2, kq = t & 3;
      long gr = m0 + row;
      if (AF32){
        float4 a = {0.f,0.f,0.f,0.f};
        if (gr < M) a = *(const float4*)(Af + gr*(long)K + k0 + kq*4);
        As[kq*4+0][row]=a.x; As[kq*4+1][row]=a.y; As[kq*4+2][row]=a.z; As[kq*4+3][row]=a.w;
      } else {
        bf16x4 a;
#pragma unroll
        for (int j=0;j<4;j++) a[j] = (__bf16)0.0f;
        if (gr < M) a = *(const bf16x4*)(Ab + gr*(long)K + k0 + kq*4);
#pragma unroll
        for (int j=0;j<4;j++) As[kq*4+j][row] = (float)a[j];
      }
    }
    {
      int kk = t >> 4, nq = t & 15;
      float4 w = *(const float4*)(W + (long)(k0+kk)*Nn + n0 + nq*4);
      *(float4*)&Bs[kk][nq*4] = w;
    }
    __syncthreads();
#pragma unroll
    for (int kk=0;kk<16;kk++){
      f32x4 a = *(const f32x4*)&As[kk][ty*4];
      f32x4 b = *(const f32x4*)&Bs[kk][tx*4];
#pragma unroll
      for (int i=0;i<4;i++)
#pragma unroll
        for (int j=0;j<4;j++) acc[i][j] += a[i]*b[j];
    }
  }

#pragma unroll
  for (int i=0;i<4;i++){
    long row = m0 + ty*4 + i;
    if (row < M){
      ushort4 v; v.x=f2bf(acc[i][0]); v.y=f2bf(acc[i][1]);
      v.z=f2bf(acc[i][2]); v.w=f2bf(acc[i][3]);
      *(ushort4*)(C + row*(long)Nn + n0 + tx*4) = v;
    }
  }
}

// ---------------------------------------------------------------- attention logits (scalar)
__global__ __launch_bounds__(256)
void k_al1s(const u16* __restrict__ xp, const float* __restrict__ a_s,
            const float* __restrict__ a_d, float* __restrict__ alS, float* __restrict__ alD)
{
  int i = blockIdx.x*256 + threadIdx.x;     // over N*NH
  if (i >= N_NODES*NH) return;
  int n = i >> 2, h = i & 3;
  const u16* row = xp + (long)n*F1 + h*HIDC;
  const float* as = a_s + h*HIDC;
  const float* ad = a_d + h*HIDC;
  float s = 0.f, d = 0.f;
  for (int c=0;c<HIDC;c++){ float x = bf2f(row[c]); s += x*as[c]; d += x*ad[c]; }
  alS[i] = s; alD[i] = d;
}

__global__ __launch_bounds__(256)
void k_al2s(const u16* __restrict__ xp, const float* __restrict__ a_s,
            const float* __restrict__ a_d, float* __restrict__ alS, float* __restrict__ alD)
{
  int n = blockIdx.x*256 + threadIdx.x;
  if (n >= N_NODES) return;
  const u16* row = xp + (long)n*F2;
  float s = 0.f, d = 0.f;
  for (int c=0;c<F2;c++){ float x = bf2f(row[c]); s += x*a_s[c]; d += x*a_d[c]; }
  alS[n] = s; alD[n] = d;
}

// ---------------------------------------------------------------- scatter GAT aggregation
__global__ __launch_bounds__(256)
void k_den1(const int* __restrict__ ei, const float* __restrict__ alS,
            const float* __restrict__ alD, float* __restrict__ den)
{
  int i = blockIdx.x*256 + threadIdx.x;
  if (i >= ETOT*NH) return;
  int e = i >> 2, h = i & 3;
  int s, d;
  if (e < E_EDGES){ s = ei[e]; d = ei[E_EDGES + e]; } else { s = d = e - E_EDGES; }
  float t = alS[s*NH+h] + alD[d*NH+h]; t = fmaxf(t, 0.2f*t);
  atomicAdd(&den[d*NH+h], __expf(t));
}

__global__ __launch_bounds__(256)
void k_scat1(const int* __restrict__ ei, const float* __restrict__ alS,
             const float* __restrict__ alD, const float* __restrict__ den,
             const u16* __restrict__ xp, float* __restrict__ agg, int half)
{
  int idx = blockIdx.x*4 + (threadIdx.x>>6);
  if (idx >= ETOT) return;
  int lane = threadIdx.x & 63;
  int s, d;
  if (idx < E_EDGES){ s = ei[idx]; d = ei[E_EDGES + idx]; } else { s = d = idx - E_EDGES; }
  int col = half*256 + lane*4;
  int h = col >> 7;
  float t = alS[s*NH+h] + alD[d*NH+h]; t = fmaxf(t, 0.2f*t);
  float w = __expf(t) / (den[d*NH+h] + SM_EPS);
  bf16x4 xv = *(const bf16x4*)(xp + (long)s*F1 + col);
  float* ap = agg + (long)d*256 + lane*4;
#pragma unroll
  for (int j=0;j<4;j++) atomicAdd(&ap[j], w*(float)xv[j]);
}

__global__ __launch_bounds__(256)
void k_merge1(const float* __restrict__ agg, const float* __restrict__ b1,
              u16* __restrict__ h1, int half)
{
  int n = blockIdx.x, c = threadIdx.x;
  long o = (long)n*F1 + half*256 + c;
  float v = agg[(long)n*256 + c] + b1[c];
  v = (v > 0.f) ? v : (__expf(v) - 1.f);
  h1[o] = f2bf(bf2f(h1[o]) + v);
}

__global__ __launch_bounds__(256)
void k_den2(const int* __restrict__ ei, const float* __restrict__ alS,
            const float* __restrict__ alD, float* __restrict__ den)
{
  int e = blockIdx.x*256 + threadIdx.x;
  if (e >= ETOT) return;
  int s, d;
  if (e < E_EDGES){ s = ei[e]; d = ei[E_EDGES + e]; } else { s = d = e - E_EDGES; }
  float t = alS[s] + alD[d]; t = fmaxf(t, 0.2f*t);
  atomicAdd(&den[d], __expf(t));
}

__global__ __launch_bounds__(256)
void k_scat2(const int* __restrict__ ei, const float* __restrict__ alS,
             const float* __restrict__ alD, const float* __restrict__ den,
             const u16* __restrict__ xp, float* __restrict__ agg)
{
  int idx = blockIdx.x*4 + (threadIdx.x>>6);
  if (idx >= ETOT) return;
  int lane = threadIdx.x & 63;
  int s, d;
  if (idx < E_EDGES){ s = ei[idx]; d = ei[E_EDGES + idx]; } else { s = d = idx - E_EDGES; }
  float t = alS[s] + alD[d]; t = fmaxf(t, 0.2f*t);
  float w = __expf(t) / (den[d] + SM_EPS);
  bf16x4 xv = *(const bf16x4*)(xp + (long)s*F2 + lane*4);
  float* ap = agg + (long)d*F2 + lane*4;
#pragma unroll
  for (int j=0;j<4;j++) atomicAdd(&ap[j], w*(float)xv[j]);
}

__global__ __launch_bounds__(256)
void k_merge2(const float* __restrict__ agg, const float* __restrict__ b2,
              u16* __restrict__ h2)
{
  int n = blockIdx.x, c = threadIdx.x;
  long o = (long)n*F2 + c;
  h2[o] = f2bf(bf2f(h2[o]) + agg[o] + b2[c]);
}

// ---------------------------------------------------------------- final residual + LN  (f32 OUTPUT)
__global__ __launch_bounds__(256)
void k_final(const u16* __restrict__ h2, const float* __restrict__ res_b,
             const float* __restrict__ g, const float* __restrict__ bb,
             float* __restrict__ out)
{
  const int n = blockIdx.x, c = threadIdx.x;
  const int lane = c & 63, wv = c >> 6;
  float y = bf2f(h2[(long)n*F2 + c]) + res_b[c];
  float s1 = y, s2 = y*y;
#pragma unroll
  for (int o=32;o>0;o>>=1){ s1 += __shfl_down(s1,o); s2 += __shfl_down(s2,o); }
  __shared__ float l1[4], l2[4];
  if (lane==0){ l1[wv]=s1; l2[wv]=s2; }
  __syncthreads();
  float t1 = l1[0]+l1[1]+l1[2]+l1[3];
  float t2 = l2[0]+l2[1]+l2[2]+l2[3];
  float mu  = t1 * (1.f/F2);
  float var = t2 * (1.f/F2) - mu*mu;
  float rs  = rsqrtf(var + LN_EPS);
  out[(long)n*F2 + c] = (y - mu) * rs * g[c] + bb[c];
}

// ---------------------------------------------------------------- utils
__global__ void k_zero16(u16* p, long n){
  long i = (long)blockIdx.x*256+threadIdx.x; if (i<n) p[i]=0;
}
__global__ void k_fillf(float* p, long n, float v){
  long i = (long)blockIdx.x*256+threadIdx.x; if (i<n) p[i]=v;
}

// ---------------------------------------------------------------- launch
extern "C" void kernel_launch(void* const* d_in, const int* in_sizes, int n_in,
                              void* d_out, int out_size, void* d_ws, size_t ws_size,
                              hipStream_t stream)
{
  float* out = (float*)d_out;          // f32 output (reference output dtype)
  const long NOUT = (long)out_size;

  // input count/order guard (proven to hold in R6; cheap insurance)
  static const int exp_sizes[14] = {6400000, 524288, 4096, 4096, 4096, 1048576,
                                    2048, 2048, 2048, 32768, 256, 256, 256, 3200000};
  float sent = 0.f;
  if (n_in != 14) sent = 450.f;
  else for (int i=0;i<14;i++) if (in_sizes[i] != exp_sizes[i]){ sent = 500.f + 10.f*i; break; }
  if (sent != 0.f){
    k_fillf<<<(int)((NOUT+255)/256),256,0,stream>>>(out, NOUT, sent);
    return;
  }

  const float* emb   = (const float*)d_in[0];
  const float* W1    = (const float*)d_in[1];
  const float* a_s1  = (const float*)d_in[2];
  const float* a_d1  = (const float*)d_in[3];
  const float* b1    = (const float*)d_in[4];
  const float* W2    = (const float*)d_in[5];
  const float* a_s2  = (const float*)d_in[6];
  const float* a_d2  = (const float*)d_in[7];
  const float* b2    = (const float*)d_in[8];
  const float* resW  = (const float*)d_in[9];
  const float* res_b = (const float*)d_in[10];
  const float* ln_g  = (const float*)d_in[11];
  const float* ln_b  = (const float*)d_in[12];
  const int*   ei    = (const int*)d_in[13];

  // workspace (~182 MB; proven to run)
  char* base = (char*)d_ws; size_t o_ = 0;
  auto alloc = [&](size_t bytes)->void*{
    void* q = base + o_; o_ += (bytes + 255) & ~(size_t)255; return q;
  };
  float* alS  = (float*)alloc((size_t)N_NODES*NH*4);
  float* alD  = (float*)alloc((size_t)N_NODES*NH*4);
  float* den  = (float*)alloc((size_t)N_NODES*NH*4);
  u16*   xp   = (u16*)  alloc((size_t)N_NODES*F1*2);
  u16*   h1   = (u16*)  alloc((size_t)N_NODES*F1*2);
  u16*   h2   = (u16*)  alloc((size_t)N_NODES*F2*2);
  float* agg  = (float*)alloc((size_t)N_NODES*256*4);
  if (o_ > ws_size){
    k_fillf<<<(int)((NOUT+255)/256),256,0,stream>>>(out, NOUT, 250.f);
    return;
  }

  k_zero16<<<(int)(((long)N_NODES*F1+255)/256),256,0,stream>>>(h1, (long)N_NODES*F1);

  const int GM64 = (N_NODES + 63)/64;  // 782
  const int GS   = (ETOT + 3)/4;       // 62500

  // ---- residual projection -> h2 (bf16)
  k_vgemm<true><<<dim3(F2/64, GM64),256,0,stream>>>(nullptr, emb, resW, h2, N_NODES, D_INP, F2);

  // ---- layer 1
  for (int r=0;r<R_REL;r++){
    const int* eir = ei + (size_t)r*2*E_EDGES;
    k_vgemm<true><<<dim3(F1/64, GM64),256,0,stream>>>(nullptr, emb, W1 + (size_t)r*D_INP*F1,
                                                      xp, N_NODES, D_INP, F1);
    k_al1s<<<(N_NODES*NH+255)/256,256,0,stream>>>(xp, a_s1 + (size_t)r*NH*HIDC,
                                                  a_d1 + (size_t)r*NH*HIDC, alS, alD);
    hipMemsetAsync(den, 0, (size_t)N_NODES*NH*4, stream);
    k_den1<<<(ETOT*NH+255)/256,256,0,stream>>>(eir, alS, alD, den);
    for (int half=0; half<2; half++){
      hipMemsetAsync(agg, 0, (size_t)N_NODES*256*4, stream);
      k_scat1<<<GS,256,0,stream>>>(eir, alS, alD, den, xp, agg, half);
      k_merge1<<<N_NODES,256,0,stream>>>(agg, b1 + (size_t)r*F1 + half*256, h1, half);
    }
  }

  // ---- layer 2
  for (int r=0;r<R_REL;r++){
    const int* eir = ei + (size_t)r*2*E_EDGES;
    k_vgemm<false><<<dim3(F2/64, GM64),256,0,stream>>>(h1, nullptr, W2 + (size_t)r*F1*F2,
                                                       xp, N_NODES, F1, F2);
    k_al2s<<<(N_NODES+255)/256,256,0,stream>>>(xp, a_s2 + (size_t)r*F2, a_d2 + (size_t)r*F2, alS, alD);
    hipMemsetAsync(den, 0, (size_t)N_NODES*4, stream);
    k_den2<<<(ETOT+255)/256,256,0,stream>>>(eir, alS, alD, den);
    hipMemsetAsync(agg, 0, (size_t)N_NODES*256*4, stream);
    k_scat2<<<GS,256,0,stream>>>(eir, alS, alD, den, xp, agg);
    k_merge2<<<N_NODES,256,0,stream>>>(agg, b2 + (size_t)r*F2, h2);
  }

  // ---- layernorm epilogue (writes f32 output)
  k_final<<<N_NODES,256,0,stream>>>(h2, res_b, ln_g, ln_b, out);
}

// Round 8
// 2069.509 us; speedup vs baseline: 11.3980x; 11.3980x over previous
//
#include <hip/hip_runtime.h>
#include <hip/hip_bf16.h>

#define N_NODES 50000
#define R_REL   8
#define E_EDGES 200000
#define ETOT    (E_EDGES + N_NODES)   // 250000 per relation (incl self loops)
#define D_INP   128
#define HIDC    128
#define NH      4
#define F1      (NH*HIDC)             // 512
#define F2      256
#define LN_EPS  1e-5f
#define SM_EPS  1e-16f

typedef unsigned short u16;
typedef __bf16 bf16x8 __attribute__((ext_vector_type(8)));
typedef __bf16 bf16x4 __attribute__((ext_vector_type(4)));
typedef float  f32x4  __attribute__((ext_vector_type(4)));

__device__ __forceinline__ float bf2f(u16 u){
  union { unsigned int i; float f; } v; v.i = ((unsigned int)u) << 16; return v.f;
}
__device__ __forceinline__ u16 f2bf(float f){
  union { float f; unsigned int i; } v; v.f = f;
  unsigned int r = v.i + 0x7FFFu + ((v.i >> 16) & 1u);
  return (u16)(r >> 16);
}

// ---------------------------------------------------------------- MFMA GEMM
// C[M,Nn] = A[M,K](bf16) * Bt[Nn,K](bf16)^T ; f32 accum; bf16 or f32 out.
// 128x128 tile, 4 waves (2x2), 16x16x32 MFMA, XOR-swizzled LDS.
template<bool F32OUT>
__global__ __launch_bounds__(256)
void k_gemm(const u16* __restrict__ A, const u16* __restrict__ Bt,
            u16* __restrict__ C, float* __restrict__ Cf, int M, int K, int Nn)
{
  __shared__ __align__(16) u16 As[128][32];
  __shared__ __align__(16) u16 Bs[128][32];
  const int tid  = threadIdx.x;
  const int lane = tid & 63, wv = tid >> 6;
  const int wr = wv >> 1, wc = wv & 1;
  const long bm = (long)blockIdx.y * 128, bn = (long)blockIdx.x * 128;

  f32x4 acc[4][4];
#pragma unroll
  for (int m=0;m<4;m++)
#pragma unroll
    for (int n=0;n<4;n++) acc[m][n] = (f32x4){0.f,0.f,0.f,0.f};

  for (int k0 = 0; k0 < K; k0 += 32) {
    __syncthreads();
#pragma unroll
    for (int i=0;i<2;i++){
      int c   = tid + 256*i;
      int row = c >> 2, ch = c & 3;
      int sw  = ch ^ ((row >> 1) & 3);          // bank-conflict swizzle
      long gr = bm + row;
      bf16x8 va;
#pragma unroll
      for (int j=0;j<8;j++) va[j] = (__bf16)0.0f;
      if (gr < M) va = *(const bf16x8*)(A + gr*(long)K + k0 + ch*8);
      *(bf16x8*)(&As[row][sw*8]) = va;
      bf16x8 vb = *(const bf16x8*)(Bt + (bn + row)*(long)K + k0 + ch*8);
      *(bf16x8*)(&Bs[row][sw*8]) = vb;
    }
    __syncthreads();
    const int ch = lane >> 4, rl = lane & 15;
    bf16x8 af[4], bfr[4];
#pragma unroll
    for (int m=0;m<4;m++){
      int row = wr*64 + m*16 + rl;
      af[m] = *(const bf16x8*)(&As[row][(ch ^ ((row >> 1) & 3))*8]);
    }
#pragma unroll
    for (int n=0;n<4;n++){
      int row = wc*64 + n*16 + rl;
      bfr[n] = *(const bf16x8*)(&Bs[row][(ch ^ ((row >> 1) & 3))*8]);
    }
#pragma unroll
    for (int m=0;m<4;m++)
#pragma unroll
      for (int n=0;n<4;n++)
        acc[m][n] = __builtin_amdgcn_mfma_f32_16x16x32_bf16(af[m], bfr[n], acc[m][n], 0,0,0);
  }
  // C/D layout: col=lane&15, row=(lane>>4)*4+reg  [m89-verified]
  const int rl = lane & 15, rg = lane >> 4;
#pragma unroll
  for (int m=0;m<4;m++)
#pragma unroll
    for (int n=0;n<4;n++)
#pragma unroll
      for (int q=0;q<4;q++){
        long row = bm + wr*64 + m*16 + rg*4 + q;
        long col = bn + wc*64 + n*16 + rl;
        if (row < M){
          if (F32OUT) Cf[row*(long)Nn + col] = acc[m][n][q];
          else        C [row*(long)Nn + col] = f2bf(acc[m][n][q]);
        }
      }
}

// ---------------------------------------------------------------- attention logits (scalar, proven)
__global__ __launch_bounds__(256)
void k_al1s(const u16* __restrict__ xp, const float* __restrict__ a_s,
            const float* __restrict__ a_d, float* __restrict__ alS, float* __restrict__ alD)
{
  int i = blockIdx.x*256 + threadIdx.x;     // over N*NH
  if (i >= N_NODES*NH) return;
  int n = i >> 2, h = i & 3;
  const u16* row = xp + (long)n*F1 + h*HIDC;
  const float* as = a_s + h*HIDC;
  const float* ad = a_d + h*HIDC;
  float s = 0.f, d = 0.f;
  for (int c=0;c<HIDC;c++){ float x = bf2f(row[c]); s += x*as[c]; d += x*ad[c]; }
  alS[i] = s; alD[i] = d;
}

__global__ __launch_bounds__(256)
void k_al2s(const u16* __restrict__ xp, const float* __restrict__ a_s,
            const float* __restrict__ a_d, float* __restrict__ alS, float* __restrict__ alD)
{
  int n = blockIdx.x*256 + threadIdx.x;
  if (n >= N_NODES) return;
  const u16* row = xp + (long)n*F2;
  float s = 0.f, d = 0.f;
  for (int c=0;c<F2;c++){ float x = bf2f(row[c]); s += x*a_s[c]; d += x*a_d[c]; }
  alS[n] = s; alD[n] = d;
}

// ---------------------------------------------------------------- edge aggregation (gather, CSR by dst)
// 2-pass (denominator, accumulate); logits ~0.02 so exp w/o max-sub is safe (proven R7).
__global__ __launch_bounds__(64)
void k_edge1(const int* __restrict__ off, const int* __restrict__ el,
             const float* __restrict__ alS, const float* __restrict__ alD,
             const u16* __restrict__ xp, const float* __restrict__ b1,
             u16* __restrict__ h1)
{
  const int d = blockIdx.x, lane = threadIdx.x;
  const int h = lane >> 4;                     // lane owns cols [8*lane, 8*lane+8) -> head constant
  const int beg = off[d], end = off[d+1];
  const float ald = alD[d*NH + h];

  float dn = 0.f;
  for (int e=beg;e<end;e++){
    int s = el[e];
    float t = alS[s*NH + h] + ald; t = fmaxf(t, 0.2f*t);
    dn += __expf(t);
  }
  const float iv = 1.f/(dn + SM_EPS);

  float acc[8];
#pragma unroll
  for (int j=0;j<8;j++) acc[j]=0.f;
  for (int e=beg;e<end;e++){
    int s = el[e];
    float t = alS[s*NH + h] + ald; t = fmaxf(t, 0.2f*t);
    float w = __expf(t) * iv;
    bf16x8 xv = *(const bf16x8*)(xp + (long)s*F1 + 8*lane);
#pragma unroll
    for (int j=0;j<8;j++) acc[j] += w * (float)xv[j];
  }
  u16* hr = h1 + (long)d*F1 + 8*lane;
  bf16x8 hv = *(bf16x8*)hr;
#pragma unroll
  for (int j=0;j<8;j++){
    float o = acc[j] + b1[8*lane + j];
    o = (o > 0.f) ? o : (__expf(o) - 1.f);     // elu
    hv[j] = (__bf16)((float)hv[j] + o);        // bf16 accumulation across relations
  }
  *(bf16x8*)hr = hv;
}

__global__ __launch_bounds__(64)
void k_edge2(const int* __restrict__ off, const int* __restrict__ el,
             const float* __restrict__ alS, const float* __restrict__ alD,
             const u16* __restrict__ xp, const float* __restrict__ b2,
             float* __restrict__ h2)
{
  const int d = blockIdx.x, lane = threadIdx.x;
  const int beg = off[d], end = off[d+1];
  const float ald = alD[d];

  float dn = 0.f;
  for (int e=beg;e<end;e++){
    float t = alS[el[e]] + ald; t = fmaxf(t, 0.2f*t);
    dn += __expf(t);
  }
  const float iv = 1.f/(dn + SM_EPS);

  float acc[4];
#pragma unroll
  for (int j=0;j<4;j++) acc[j]=0.f;
  for (int e=beg;e<end;e++){
    int s = el[e];
    float t = alS[s] + ald; t = fmaxf(t, 0.2f*t);
    float w = __expf(t) * iv;
    bf16x4 xv = *(const bf16x4*)(xp + (long)s*F2 + 4*lane);
#pragma unroll
    for (int j=0;j<4;j++) acc[j] += w * (float)xv[j];
  }
  float* hr = h2 + (long)d*F2 + 4*lane;
#pragma unroll
  for (int j=0;j<4;j++) hr[j] += acc[j] + b2[4*lane + j];
}

// ---------------------------------------------------------------- final residual + LN (f32 out)
__global__ __launch_bounds__(256)
void k_final(const float* __restrict__ h2, const float* __restrict__ res_b,
             const float* __restrict__ g, const float* __restrict__ bb,
             float* __restrict__ out)
{
  const int n = blockIdx.x, c = threadIdx.x;
  const int lane = c & 63, wv = c >> 6;
  float y = h2[(long)n*F2 + c] + res_b[c];
  float s1 = y, s2 = y*y;
#pragma unroll
  for (int o=32;o>0;o>>=1){ s1 += __shfl_down(s1,o); s2 += __shfl_down(s2,o); }
  __shared__ float l1[4], l2[4];
  if (lane==0){ l1[wv]=s1; l2[wv]=s2; }
  __syncthreads();
  float t1 = l1[0]+l1[1]+l1[2]+l1[3];
  float t2 = l2[0]+l2[1]+l2[2]+l2[3];
  float mu  = t1 * (1.f/F2);
  float var = t2 * (1.f/F2) - mu*mu;
  float rs  = rsqrtf(var + LN_EPS);
  out[(long)n*F2 + c] = (y - mu) * rs * g[c] + bb[c];
}

// ---------------------------------------------------------------- utils
// transpose + f32->bf16: Wt[n*K+k] = bf16(W[k*Nn+n])
__global__ void k_transpose(const float* __restrict__ W, u16* __restrict__ Wt, int K, int Nn)
{
  int t = blockIdx.x*256 + threadIdx.x;
  if (t < K*Nn){ int nn = t / K, kk = t - nn*K; Wt[t] = f2bf(W[(long)kk*Nn + nn]); }
}
__global__ __launch_bounds__(256)
void k_cvt(const float* __restrict__ s, u16* __restrict__ d, long n)
{
  long i = ((long)blockIdx.x*256 + threadIdx.x)*4;
  if (i < n){
    float4 v = *(const float4*)(s + i);
    ushort4 o; o.x=f2bf(v.x); o.y=f2bf(v.y); o.z=f2bf(v.z); o.w=f2bf(v.w);
    *(ushort4*)(d + i) = o;
  }
}
__global__ void k_zero16(u16* p, long n){
  long i = (long)blockIdx.x*256+threadIdx.x; if (i<n) p[i]=0;
}
__global__ void k_fillf(float* p, long n, float v){
  long i = (long)blockIdx.x*256+threadIdx.x; if (i<n) p[i]=v;
}

// ---------------------------------------------------------------- CSR build (R3, audited)
__global__ void k_seti(int* p, int v, int n){
  int i = blockIdx.x*256+threadIdx.x; if (i<n) p[i]=v;
}
__global__ void k_count(const int* __restrict__ ei, int* __restrict__ cnt){
  int i = blockIdx.x*256+threadIdx.x;
  if (i < R_REL*E_EDGES){
    int r = i / E_EDGES, e = i - r*E_EDGES;
    int dd = ei[(long)r*2*E_EDGES + E_EDGES + e];
    atomicAdd(&cnt[r*N_NODES + dd], 1);
  }
}
#define SCAN_CHUNK 1024
#define NBLK 49          // ceil(50000/1024)
__global__ __launch_bounds__(256)
void k_scan1(const int* __restrict__ cnt, int* __restrict__ bs){
  int r = blockIdx.x / NBLK, b = blockIdx.x - r*NBLK;
  int base = b*SCAN_CHUNK + threadIdx.x*4;
  int s = 0;
#pragma unroll
  for (int i=0;i<4;i++){ int idx = base+i; if (idx<N_NODES) s += cnt[r*N_NODES+idx]; }
  __shared__ int sm[256];
  sm[threadIdx.x]=s; __syncthreads();
  for (int o=128;o>0;o>>=1){ if (threadIdx.x<o) sm[threadIdx.x]+=sm[threadIdx.x+o]; __syncthreads(); }
  if (threadIdx.x==0) bs[r*64+b] = sm[0];
}
__global__ void k_scan2(int* bs, int* off){
  int r = blockIdx.x;
  if (threadIdx.x==0){
    int run=0;
    for (int i=0;i<NBLK;i++){ int t=bs[r*64+i]; bs[r*64+i]=run; run+=t; }
    off[(long)r*(N_NODES+1) + N_NODES] = run;
  }
}
__global__ __launch_bounds__(256)
void k_scan3(const int* __restrict__ cnt, const int* __restrict__ bs, int* __restrict__ off){
  int r = blockIdx.x / NBLK, b = blockIdx.x - r*NBLK;
  int tid = threadIdx.x;
  int base = b*SCAN_CHUNK + tid*4;
  int v[4]; int ts=0;
#pragma unroll
  for (int i=0;i<4;i++){ int idx=base+i; v[i] = (idx<N_NODES)? cnt[r*N_NODES+idx] : 0; ts+=v[i]; }
  __shared__ int sm[256];
  sm[tid]=ts; __syncthreads();
  for (int o=1;o<256;o<<=1){
    int add = (tid>=o)? sm[tid-o] : 0;
    __syncthreads();
    sm[tid] += add;
    __syncthreads();
  }
  int run = bs[r*64+b] + (sm[tid] - ts);
#pragma unroll
  for (int i=0;i<4;i++){ int idx=base+i; if (idx<N_NODES) off[(long)r*(N_NODES+1)+idx] = run; run += v[i]; }
}
__global__ void k_cursor(const int* __restrict__ off, int* __restrict__ cur){
  int i = blockIdx.x*256+threadIdx.x;
  if (i < R_REL*N_NODES){ int r=i/N_NODES, nn=i-r*N_NODES; cur[i] = off[(long)r*(N_NODES+1)+nn]; }
}
__global__ void k_scat_self(int* cur, int* el){
  int i = blockIdx.x*256+threadIdx.x;
  if (i < R_REL*N_NODES){
    int r=i/N_NODES, nn=i-r*N_NODES;
    int p = atomicAdd(&cur[i],1);
    el[(long)r*ETOT + p] = nn;
  }
}
__global__ void k_scat_edge(const int* __restrict__ ei, int* cur, int* el){
  int i = blockIdx.x*256+threadIdx.x;
  if (i < R_REL*E_EDGES){
    int r = i / E_EDGES, e = i - r*E_EDGES;
    int ss = ei[(long)r*2*E_EDGES + e];
    int dd = ei[(long)r*2*E_EDGES + E_EDGES + e];
    int p = atomicAdd(&cur[r*N_NODES+dd],1);
    el[(long)r*ETOT + p] = ss;
  }
}

// ---------------------------------------------------------------- launch
extern "C" void kernel_launch(void* const* d_in, const int* in_sizes, int n_in,
                              void* d_out, int out_size, void* d_ws, size_t ws_size,
                              hipStream_t stream)
{
  float* out = (float*)d_out;          // f32 output (reference output dtype) — R7-proven
  const long NOUT = (long)out_size;

  static const int exp_sizes[14] = {6400000, 524288, 4096, 4096, 4096, 1048576,
                                    2048, 2048, 2048, 32768, 256, 256, 256, 3200000};
  float sent = 0.f;
  if (n_in != 14) sent = 450.f;
  else for (int i=0;i<14;i++) if (in_sizes[i] != exp_sizes[i]){ sent = 500.f + 10.f*i; break; }
  if (sent != 0.f){
    k_fillf<<<(int)((NOUT+255)/256),256,0,stream>>>(out, NOUT, sent);
    return;
  }

  const float* emb   = (const float*)d_in[0];
  const float* W1    = (const float*)d_in[1];
  const float* a_s1  = (const float*)d_in[2];
  const float* a_d1  = (const float*)d_in[3];
  const float* b1    = (const float*)d_in[4];
  const float* W2    = (const float*)d_in[5];
  const float* a_s2  = (const float*)d_in[6];
  const float* a_d2  = (const float*)d_in[7];
  const float* b2    = (const float*)d_in[8];
  const float* resW  = (const float*)d_in[9];
  const float* res_b = (const float*)d_in[10];
  const float* ln_g  = (const float*)d_in[11];
  const float* ln_b  = (const float*)d_in[12];
  const int*   ei    = (const int*)d_in[13];

  // workspace carve-up (~180 MB; <= 181.6 MB proven in R6/R7)
  char* base = (char*)d_ws; size_t o_ = 0;
  auto alloc = [&](size_t bytes)->void*{
    void* q = base + o_; o_ += (bytes + 255) & ~(size_t)255; return q;
  };
  int*   off  = (int*)  alloc((size_t)R_REL*(N_NODES+1)*4);  // 1.6 MB
  int*   cur  = (int*)  alloc((size_t)R_REL*N_NODES*4);      // 1.6 MB
  int*   el   = (int*)  alloc((size_t)R_REL*ETOT*4);         // 8 MB
  int*   bs   = (int*)  alloc((size_t)R_REL*64*4);
  float* alS  = (float*)alloc((size_t)N_NODES*NH*4);         // 0.8 MB
  float* alD  = (float*)alloc((size_t)N_NODES*NH*4);         // 0.8 MB
  u16*   embb = (u16*)  alloc((size_t)N_NODES*D_INP*2);      // 12.8 MB
  u16*   xp   = (u16*)  alloc((size_t)N_NODES*F1*2);         // 51.2 MB
  u16*   h1   = (u16*)  alloc((size_t)N_NODES*F1*2);         // 51.2 MB (bf16 acc)
  float* h2   = (float*)alloc((size_t)N_NODES*F2*4);         // 51.2 MB (f32 acc)
  u16*   Wt   = (u16*)  alloc((size_t)512*512*2);            // 0.5 MB
  if (o_ > ws_size){
    k_fillf<<<(int)((NOUT+255)/256),256,0,stream>>>(out, NOUT, 250.f);
    return;
  }

  int g;
  k_cvt<<<(int)(((long)N_NODES*D_INP/4+255)/256),256,0,stream>>>(emb, embb, (long)N_NODES*D_INP);
  k_zero16<<<(int)(((long)N_NODES*F1+255)/256),256,0,stream>>>(h1, (long)N_NODES*F1);

  // ---- CSR build (dst-sorted adjacency, shared by both layers)
  g = (R_REL*N_NODES+255)/256; k_seti<<<g,256,0,stream>>>(cur, 1, R_REL*N_NODES);  // self-loop counts
  g = (R_REL*E_EDGES+255)/256; k_count<<<g,256,0,stream>>>(ei, cur);
  k_scan1<<<R_REL*NBLK,256,0,stream>>>(cur, bs);
  k_scan2<<<R_REL,64,0,stream>>>(bs, off);
  k_scan3<<<R_REL*NBLK,256,0,stream>>>(cur, bs, off);
  g = (R_REL*N_NODES+255)/256; k_cursor<<<g,256,0,stream>>>(off, cur);
  k_scat_self<<<g,256,0,stream>>>(cur, el);
  g = (R_REL*E_EDGES+255)/256; k_scat_edge<<<g,256,0,stream>>>(ei, cur, el);

  const int GM = (N_NODES + 127)/128;  // 391

  // ---- residual projection (writes h2 in f32, initializing it)
  g = (D_INP*F2+255)/256;
  k_transpose<<<g,256,0,stream>>>(resW, Wt, D_INP, F2);
  k_gemm<true><<<dim3(F2/128, GM),256,0,stream>>>(embb, Wt, nullptr, h2, N_NODES, D_INP, F2);

  // ---- layer 1
  for (int r=0;r<R_REL;r++){
    g = (D_INP*F1+255)/256;
    k_transpose<<<g,256,0,stream>>>(W1 + (size_t)r*D_INP*F1, Wt, D_INP, F1);
    k_gemm<false><<<dim3(F1/128, GM),256,0,stream>>>(embb, Wt, xp, nullptr, N_NODES, D_INP, F1);
    k_al1s<<<(N_NODES*NH+255)/256,256,0,stream>>>(xp, a_s1 + (size_t)r*NH*HIDC,
                                                  a_d1 + (size_t)r*NH*HIDC, alS, alD);
    k_edge1<<<N_NODES,64,0,stream>>>(off + (size_t)r*(N_NODES+1), el + (size_t)r*ETOT,
                                     alS, alD, xp, b1 + (size_t)r*F1, h1);
  }

  // ---- layer 2 (reads bf16 h1 directly)
  for (int r=0;r<R_REL;r++){
    g = (F1*F2+255)/256;
    k_transpose<<<g,256,0,stream>>>(W2 + (size_t)r*F1*F2, Wt, F1, F2);
    k_gemm<false><<<dim3(F2/128, GM),256,0,stream>>>(h1, Wt, xp, nullptr, N_NODES, F1, F2);
    k_al2s<<<(N_NODES+255)/256,256,0,stream>>>(xp, a_s2 + (size_t)r*F2, a_d2 + (size_t)r*F2, alS, alD);
    k_edge2<<<N_NODES,64,0,stream>>>(off + (size_t)r*(N_NODES+1), el + (size_t)r*ETOT,
                                     alS, alD, xp, b2 + (size_t)r*F2, h2);
  }

  // ---- layernorm epilogue (f32 output)
  k_final<<<N_NODES,256,0,stream>>>(h2, res_b, ln_g, ln_b, out);
}

// Round 10
// 1756.420 us; speedup vs baseline: 13.4297x; 1.1783x over previous
//
#include <hip/hip_runtime.h>
#include <hip/hip_bf16.h>

#define N_NODES 50000
#define R_REL   8
#define E_EDGES 200000
#define ETOT    (E_EDGES + N_NODES)   // 250000 per relation (incl self loops)
#define D_INP   128
#define HIDC    128
#define NH      4
#define F1      (NH*HIDC)             // 512
#define F2      256
#define LN_EPS  1e-5f
#define SM_EPS  1e-16f

typedef unsigned short u16;
typedef __bf16 bf16x8 __attribute__((ext_vector_type(8)));
typedef __bf16 bf16x4 __attribute__((ext_vector_type(4)));
typedef float  f32x4  __attribute__((ext_vector_type(4)));

__device__ __forceinline__ float bf2f(u16 u){
  union { unsigned int i; float f; } v; v.i = ((unsigned int)u) << 16; return v.f;
}
__device__ __forceinline__ u16 f2bf(float f){
  union { float f; unsigned int i; } v; v.f = f;
  unsigned int r = v.i + 0x7FFFu + ((v.i >> 16) & 1u);
  return (u16)(r >> 16);
}

// ---------------------------------------------------------------- MFMA GEMM
// C[M,Nn] = A[M,K](bf16) * Bt[Nn,K](bf16)^T ; f32 accum; bf16 or f32 out.
// 128x128 tile, 4 waves (2x2), 16x16x32 MFMA.
// Staging via global_load_lds width=16: linear LDS dest (slot c at byte c*16),
// pre-swizzled global source ch = blk ^ ((row>>1)&3)  -> LDS content identical
// to R8's verified layout; compute path unchanged.
template<bool F32OUT>
__global__ __launch_bounds__(256)
void k_gemm(const u16* __restrict__ A, const u16* __restrict__ Bt,
            u16* __restrict__ C, float* __restrict__ Cf, int M, int K, int Nn)
{
  __shared__ __align__(16) u16 As[128][32];
  __shared__ __align__(16) u16 Bs[128][32];
  const int tid  = threadIdx.x;
  const int lane = tid & 63, wv = tid >> 6;
  const int wr = wv >> 1, wc = wv & 1;
  const long bm = (long)blockIdx.y * 128, bn = (long)blockIdx.x * 128;

  f32x4 acc[4][4];
#pragma unroll
  for (int m=0;m<4;m++)
#pragma unroll
    for (int n=0;n<4;n++) acc[m][n] = (f32x4){0.f,0.f,0.f,0.f};

  for (int k0 = 0; k0 < K; k0 += 32) {
    __syncthreads();
#pragma unroll
    for (int i=0;i<2;i++){
      int c   = tid + 256*i;
      int row = c >> 2, blk = c & 3;
      int ch  = blk ^ ((row >> 1) & 3);          // pre-swizzled source chunk
      long gra = bm + row; if (gra > M-1) gra = M-1;   // clamp tail (rows>=M never stored)
      char* ldsA = (char*)&As[0][0] + ((size_t)((tid & ~63) + 256*i) * 16);
      char* ldsB = (char*)&Bs[0][0] + ((size_t)((tid & ~63) + 256*i) * 16);
      __builtin_amdgcn_global_load_lds((const unsigned int*)(A  + gra*(long)K + k0 + ch*8),
                                       (unsigned int*)ldsA, 16, 0, 0);
      __builtin_amdgcn_global_load_lds((const unsigned int*)(Bt + (bn + row)*(long)K + k0 + ch*8),
                                       (unsigned int*)ldsB, 16, 0, 0);
    }
    __syncthreads();
    const int ch = lane >> 4, rl = lane & 15;
    bf16x8 af[4], bfr[4];
#pragma unroll
    for (int m=0;m<4;m++){
      int row = wr*64 + m*16 + rl;
      af[m] = *(const bf16x8*)(&As[row][(ch ^ ((row >> 1) & 3))*8]);
    }
#pragma unroll
    for (int n=0;n<4;n++){
      int row = wc*64 + n*16 + rl;
      bfr[n] = *(const bf16x8*)(&Bs[row][(ch ^ ((row >> 1) & 3))*8]);
    }
#pragma unroll
    for (int m=0;m<4;m++)
#pragma unroll
      for (int n=0;n<4;n++)
        acc[m][n] = __builtin_amdgcn_mfma_f32_16x16x32_bf16(af[m], bfr[n], acc[m][n], 0,0,0);
  }
  // C/D layout: col=lane&15, row=(lane>>4)*4+reg  [m89-verified, R8-proven]
  const int rl = lane & 15, rg = lane >> 4;
#pragma unroll
  for (int m=0;m<4;m++)
#pragma unroll
    for (int n=0;n<4;n++)
#pragma unroll
      for (int q=0;q<4;q++){
        long row = bm + wr*64 + m*16 + rg*4 + q;
        long col = bn + wc*64 + n*16 + rl;
        if (row < M){
          if (F32OUT) Cf[row*(long)Nn + col] = acc[m][n][q];
          else        C [row*(long)Nn + col] = f2bf(acc[m][n][q]);
        }
      }
}

// ---------------------------------------------------------------- attention logits (wave-parallel, coalesced)
// layer 1: one wave per node; lane owns cols [8l,8l+8) -> head h = lane>>4 constant.
__global__ __launch_bounds__(256)
void k_al1w(const u16* __restrict__ xp, const float* __restrict__ a_s,
            const float* __restrict__ a_d, float* __restrict__ alS, float* __restrict__ alD)
{
  const int wv = threadIdx.x >> 6, lane = threadIdx.x & 63;
  const int n = blockIdx.x*4 + wv;               // 12500 blocks, N divisible by 4
  const int h = lane >> 4;
  bf16x8 x = *(const bf16x8*)(xp + (long)n*F1 + 8*lane);
  f32x4 a0 = *(const f32x4*)(a_s + 8*lane);
  f32x4 a1 = *(const f32x4*)(a_s + 8*lane + 4);
  f32x4 e0 = *(const f32x4*)(a_d + 8*lane);
  f32x4 e1 = *(const f32x4*)(a_d + 8*lane + 4);
  float s = 0.f, d = 0.f;
#pragma unroll
  for (int j=0;j<4;j++){ float xv=(float)x[j];   s += xv*a0[j]; d += xv*e0[j]; }
#pragma unroll
  for (int j=0;j<4;j++){ float xv=(float)x[4+j]; s += xv*a1[j]; d += xv*e1[j]; }
#pragma unroll
  for (int o=1;o<16;o<<=1){ s += __shfl_xor(s,o); d += __shfl_xor(d,o); }
  if ((lane & 15) == 0){ alS[n*NH+h] = s; alD[n*NH+h] = d; }
}

// layer 2: one wave per node; lane owns cols [4l,4l+4).
__global__ __launch_bounds__(256)
void k_al2w(const u16* __restrict__ xp, const float* __restrict__ a_s,
            const float* __restrict__ a_d, float* __restrict__ alS, float* __restrict__ alD)
{
  const int wv = threadIdx.x >> 6, lane = threadIdx.x & 63;
  const int n = blockIdx.x*4 + wv;
  bf16x4 x = *(const bf16x4*)(xp + (long)n*F2 + 4*lane);
  f32x4 a = *(const f32x4*)(a_s + 4*lane);
  f32x4 e = *(const f32x4*)(a_d + 4*lane);
  float s = 0.f, d = 0.f;
#pragma unroll
  for (int j=0;j<4;j++){ float xv=(float)x[j]; s += xv*a[j]; d += xv*e[j]; }
#pragma unroll
  for (int o=1;o<64;o<<=1){ s += __shfl_xor(s,o); d += __shfl_xor(d,o); }
  if (lane == 0){ alS[n] = s; alD[n] = d; }
}

// ---------------------------------------------------------------- edge aggregation (gather, CSR by dst)
__global__ __launch_bounds__(64)
void k_edge1(const int* __restrict__ off, const int* __restrict__ el,
             const float* __restrict__ alS, const float* __restrict__ alD,
             const u16* __restrict__ xp, const float* __restrict__ b1,
             u16* __restrict__ h1)
{
  const int d = blockIdx.x, lane = threadIdx.x;
  const int h = lane >> 4;
  const int beg = off[d], end = off[d+1];
  const float ald = alD[d*NH + h];

  float dn = 0.f;
  for (int e=beg;e<end;e++){
    int s = el[e];
    float t = alS[s*NH + h] + ald; t = fmaxf(t, 0.2f*t);
    dn += __expf(t);
  }
  const float iv = 1.f/(dn + SM_EPS);

  float acc[8];
#pragma unroll
  for (int j=0;j<8;j++) acc[j]=0.f;
  for (int e=beg;e<end;e++){
    int s = el[e];
    float t = alS[s*NH + h] + ald; t = fmaxf(t, 0.2f*t);
    float w = __expf(t) * iv;
    bf16x8 xv = *(const bf16x8*)(xp + (long)s*F1 + 8*lane);
#pragma unroll
    for (int j=0;j<8;j++) acc[j] += w * (float)xv[j];
  }
  u16* hr = h1 + (long)d*F1 + 8*lane;
  bf16x8 hv = *(bf16x8*)hr;
#pragma unroll
  for (int j=0;j<8;j++){
    float o = acc[j] + b1[8*lane + j];
    o = (o > 0.f) ? o : (__expf(o) - 1.f);     // elu
    hv[j] = (__bf16)((float)hv[j] + o);
  }
  *(bf16x8*)hr = hv;
}

__global__ __launch_bounds__(64)
void k_edge2(const int* __restrict__ off, const int* __restrict__ el,
             const float* __restrict__ alS, const float* __restrict__ alD,
             const u16* __restrict__ xp, const float* __restrict__ b2,
             float* __restrict__ h2)
{
  const int d = blockIdx.x, lane = threadIdx.x;
  const int beg = off[d], end = off[d+1];
  const float ald = alD[d];

  float dn = 0.f;
  for (int e=beg;e<end;e++){
    float t = alS[el[e]] + ald; t = fmaxf(t, 0.2f*t);
    dn += __expf(t);
  }
  const float iv = 1.f/(dn + SM_EPS);

  float acc[4];
#pragma unroll
  for (int j=0;j<4;j++) acc[j]=0.f;
  for (int e=beg;e<end;e++){
    int s = el[e];
    float t = alS[s] + ald; t = fmaxf(t, 0.2f*t);
    float w = __expf(t) * iv;
    bf16x4 xv = *(const bf16x4*)(xp + (long)s*F2 + 4*lane);
#pragma unroll
    for (int j=0;j<4;j++) acc[j] += w * (float)xv[j];
  }
  float* hr = h2 + (long)d*F2 + 4*lane;
#pragma unroll
  for (int j=0;j<4;j++) hr[j] += acc[j] + b2[4*lane + j];
}

// ---------------------------------------------------------------- final residual + LN (f32 out)
__global__ __launch_bounds__(256)
void k_final(const float* __restrict__ h2, const float* __restrict__ res_b,
             const float* __restrict__ g, const float* __restrict__ bb,
             float* __restrict__ out)
{
  const int n = blockIdx.x, c = threadIdx.x;
  const int lane = c & 63, wv = c >> 6;
  float y = h2[(long)n*F2 + c] + res_b[c];
  float s1 = y, s2 = y*y;
#pragma unroll
  for (int o=32;o>0;o>>=1){ s1 += __shfl_down(s1,o); s2 += __shfl_down(s2,o); }
  __shared__ float l1[4], l2[4];
  if (lane==0){ l1[wv]=s1; l2[wv]=s2; }
  __syncthreads();
  float t1 = l1[0]+l1[1]+l1[2]+l1[3];
  float t2 = l2[0]+l2[1]+l2[2]+l2[3];
  float mu  = t1 * (1.f/F2);
  float var = t2 * (1.f/F2) - mu*mu;
  float rs  = rsqrtf(var + LN_EPS);
  out[(long)n*F2 + c] = (y - mu) * rs * g[c] + bb[c];
}

// ---------------------------------------------------------------- utils
// batched transpose + f32->bf16: Wt[r][nn][kk] = bf16(W[r][kk][nn])
__global__ void k_transpose_b(const float* __restrict__ W, u16* __restrict__ Wt,
                              int K, int Nn, int R)
{
  long t = (long)blockIdx.x*256 + threadIdx.x;
  long per = (long)K*Nn;
  if (t >= (long)R*per) return;
  int r = (int)(t / per); long w = t - (long)r*per;
  int nn = (int)(w / K), kk = (int)(w - (long)nn*K);
  Wt[t] = f2bf(W[(long)r*per + (long)kk*Nn + nn]);
}
__global__ __launch_bounds__(256)
void k_cvt(const float* __restrict__ s, u16* __restrict__ d, long n)
{
  long i = ((long)blockIdx.x*256 + threadIdx.x)*4;
  if (i < n){
    float4 v = *(const float4*)(s + i);
    ushort4 o; o.x=f2bf(v.x); o.y=f2bf(v.y); o.z=f2bf(v.z); o.w=f2bf(v.w);
    *(ushort4*)(d + i) = o;
  }
}
__global__ void k_zero16(u16* p, long n){
  long i = (long)blockIdx.x*256+threadIdx.x; if (i<n) p[i]=0;
}
__global__ void k_fillf(float* p, long n, float v){
  long i = (long)blockIdx.x*256+threadIdx.x; if (i<n) p[i]=v;
}

// ---------------------------------------------------------------- CSR build (R8-proven)
__global__ void k_seti(int* p, int v, int n){
  int i = blockIdx.x*256+threadIdx.x; if (i<n) p[i]=v;
}
__global__ void k_count(const int* __restrict__ ei, int* __restrict__ cnt){
  int i = blockIdx.x*256+threadIdx.x;
  if (i < R_REL*E_EDGES){
    int r = i / E_EDGES, e = i - r*E_EDGES;
    int dd = ei[(long)r*2*E_EDGES + E_EDGES + e];
    atomicAdd(&cnt[r*N_NODES + dd], 1);
  }
}
#define SCAN_CHUNK 1024
#define NBLK 49          // ceil(50000/1024)
__global__ __launch_bounds__(256)
void k_scan1(const int* __restrict__ cnt, int* __restrict__ bs){
  int r = blockIdx.x / NBLK, b = blockIdx.x - r*NBLK;
  int base = b*SCAN_CHUNK + threadIdx.x*4;
  int s = 0;
#pragma unroll
  for (int i=0;i<4;i++){ int idx = base+i; if (idx<N_NODES) s += cnt[r*N_NODES+idx]; }
  __shared__ int sm[256];
  sm[threadIdx.x]=s; __syncthreads();
  for (int o=128;o>0;o>>=1){ if (threadIdx.x<o) sm[threadIdx.x]+=sm[threadIdx.x+o]; __syncthreads(); }
  if (threadIdx.x==0) bs[r*64+b] = sm[0];
}
__global__ void k_scan2(int* bs, int* off){
  int r = blockIdx.x;
  if (threadIdx.x==0){
    int run=0;
    for (int i=0;i<NBLK;i++){ int t=bs[r*64+i]; bs[r*64+i]=run; run+=t; }
    off[(long)r*(N_NODES+1) + N_NODES] = run;
  }
}
__global__ __launch_bounds__(256)
void k_scan3(const int* __restrict__ cnt, const int* __restrict__ bs, int* __restrict__ off){
  int r = blockIdx.x / NBLK, b = blockIdx.x - r*NBLK;
  int tid = threadIdx.x;
  int base = b*SCAN_CHUNK + tid*4;
  int v[4]; int ts=0;
#pragma unroll
  for (int i=0;i<4;i++){ int idx=base+i; v[i] = (idx<N_NODES)? cnt[r*N_NODES+idx] : 0; ts+=v[i]; }
  __shared__ int sm[256];
  sm[tid]=ts; __syncthreads();
  for (int o=1;o<256;o<<=1){
    int add = (tid>=o)? sm[tid-o] : 0;
    __syncthreads();
    sm[tid] += add;
    __syncthreads();
  }
  int run = bs[r*64+b] + (sm[tid] - ts);
#pragma unroll
  for (int i=0;i<4;i++){ int idx=base+i; if (idx<N_NODES) off[(long)r*(N_NODES+1)+idx] = run; run += v[i]; }
}
__global__ void k_cursor(const int* __restrict__ off, int* __restrict__ cur){
  int i = blockIdx.x*256+threadIdx.x;
  if (i < R_REL*N_NODES){ int r=i/N_NODES, nn=i-r*N_NODES; cur[i] = off[(long)r*(N_NODES+1)+nn]; }
}
__global__ void k_scat_self(int* cur, int* el){
  int i = blockIdx.x*256+threadIdx.x;
  if (i < R_REL*N_NODES){
    int r=i/N_NODES, nn=i-r*N_NODES;
    int p = atomicAdd(&cur[i],1);
    el[(long)r*ETOT + p] = nn;
  }
}
__global__ void k_scat_edge(const int* __restrict__ ei, int* cur, int* el){
  int i = blockIdx.x*256+threadIdx.x;
  if (i < R_REL*E_EDGES){
    int r = i / E_EDGES, e = i - r*E_EDGES;
    int ss = ei[(long)r*2*E_EDGES + e];
    int dd = ei[(long)r*2*E_EDGES + E_EDGES + e];
    int p = atomicAdd(&cur[r*N_NODES+dd],1);
    el[(long)r*ETOT + p] = ss;
  }
}

// ---------------------------------------------------------------- launch
extern "C" void kernel_launch(void* const* d_in, const int* in_sizes, int n_in,
                              void* d_out, int out_size, void* d_ws, size_t ws_size,
                              hipStream_t stream)
{
  float* out = (float*)d_out;          // f32 output — R7/R8-proven
  const long NOUT = (long)out_size;

  static const int exp_sizes[14] = {6400000, 524288, 4096, 4096, 4096, 1048576,
                                    2048, 2048, 2048, 32768, 256, 256, 256, 3200000};
  float sent = 0.f;
  if (n_in != 14) sent = 450.f;
  else for (int i=0;i<14;i++) if (in_sizes[i] != exp_sizes[i]){ sent = 500.f + 10.f*i; break; }
  if (sent != 0.f){
    k_fillf<<<(int)((NOUT+255)/256),256,0,stream>>>(out, NOUT, sent);
    return;
  }

  const float* emb   = (const float*)d_in[0];
  const float* W1    = (const float*)d_in[1];
  const float* a_s1  = (const float*)d_in[2];
  const float* a_d1  = (const float*)d_in[3];
  const float* b1    = (const float*)d_in[4];
  const float* W2    = (const float*)d_in[5];
  const float* a_s2  = (const float*)d_in[6];
  const float* a_d2  = (const float*)d_in[7];
  const float* b2    = (const float*)d_in[8];
  const float* resW  = (const float*)d_in[9];
  const float* res_b = (const float*)d_in[10];
  const float* ln_g  = (const float*)d_in[11];
  const float* ln_b  = (const float*)d_in[12];
  const int*   ei    = (const int*)d_in[13];

  // workspace carve-up (~180.3 MB; <= 181.6 MB proven)
  char* base = (char*)d_ws; size_t o_ = 0;
  auto alloc = [&](size_t bytes)->void*{
    void* q = base + o_; o_ += (bytes + 255) & ~(size_t)255; return q;
  };
  int*   off   = (int*)  alloc((size_t)R_REL*(N_NODES+1)*4);  // 1.6 MB
  int*   cur   = (int*)  alloc((size_t)R_REL*N_NODES*4);      // 1.6 MB
  int*   el    = (int*)  alloc((size_t)R_REL*ETOT*4);         // 8 MB
  int*   bs    = (int*)  alloc((size_t)R_REL*64*4);
  float* alS   = (float*)alloc((size_t)N_NODES*NH*4);         // 0.8 MB
  float* alD   = (float*)alloc((size_t)N_NODES*NH*4);         // 0.8 MB
  u16*   embb  = (u16*)  alloc((size_t)N_NODES*D_INP*2);      // 12.8 MB
  u16*   xp    = (u16*)  alloc((size_t)N_NODES*F1*2);         // 51.2 MB
  u16*   h1    = (u16*)  alloc((size_t)N_NODES*F1*2);         // 51.2 MB (bf16 acc)
  float* h2    = (float*)alloc((size_t)N_NODES*F2*4);         // 51.2 MB (f32 acc)
  u16*   W1t   = (u16*)  alloc((size_t)R_REL*D_INP*F1*2);     // 1.05 MB
  u16*   resWt = (u16*)  alloc((size_t)D_INP*F2*2);           // 64 KB
  u16*   W2t   = embb;   // alias: embb dead after layer 1; W2t (2.1 MB) fits in 12.8 MB
  if (o_ > ws_size){
    k_fillf<<<(int)((NOUT+255)/256),256,0,stream>>>(out, NOUT, 250.f);
    return;
  }

  int g;
  k_cvt<<<(int)(((long)N_NODES*D_INP/4+255)/256),256,0,stream>>>(emb, embb, (long)N_NODES*D_INP);
  k_zero16<<<(int)(((long)N_NODES*F1+255)/256),256,0,stream>>>(h1, (long)N_NODES*F1);

  // ---- CSR build
  g = (R_REL*N_NODES+255)/256; k_seti<<<g,256,0,stream>>>(cur, 1, R_REL*N_NODES);
  g = (R_REL*E_EDGES+255)/256; k_count<<<g,256,0,stream>>>(ei, cur);
  k_scan1<<<R_REL*NBLK,256,0,stream>>>(cur, bs);
  k_scan2<<<R_REL,64,0,stream>>>(bs, off);
  k_scan3<<<R_REL*NBLK,256,0,stream>>>(cur, bs, off);
  g = (R_REL*N_NODES+255)/256; k_cursor<<<g,256,0,stream>>>(off, cur);
  k_scat_self<<<g,256,0,stream>>>(cur, el);
  g = (R_REL*E_EDGES+255)/256; k_scat_edge<<<g,256,0,stream>>>(ei, cur, el);

  // ---- batched weight transposes (W1 all relations, resW)
  k_transpose_b<<<(R_REL*D_INP*F1+255)/256,256,0,stream>>>(W1, W1t, D_INP, F1, R_REL);
  k_transpose_b<<<(D_INP*F2+255)/256,256,0,stream>>>(resW, resWt, D_INP, F2, 1);

  const int GM = (N_NODES + 127)/128;  // 391

  // ---- residual projection (f32 into h2)
  k_gemm<true><<<dim3(F2/128, GM),256,0,stream>>>(embb, resWt, nullptr, h2, N_NODES, D_INP, F2);

  // ---- layer 1
  for (int r=0;r<R_REL;r++){
    k_gemm<false><<<dim3(F1/128, GM),256,0,stream>>>(embb, W1t + (size_t)r*D_INP*F1,
                                                     xp, nullptr, N_NODES, D_INP, F1);
    k_al1w<<<N_NODES/4,256,0,stream>>>(xp, a_s1 + (size_t)r*NH*HIDC,
                                       a_d1 + (size_t)r*NH*HIDC, alS, alD);
    k_edge1<<<N_NODES,64,0,stream>>>(off + (size_t)r*(N_NODES+1), el + (size_t)r*ETOT,
                                     alS, alD, xp, b1 + (size_t)r*F1, h1);
  }

  // ---- W2 transposes (into dead embb) then layer 2
  k_transpose_b<<<(R_REL*F1*F2+255)/256,256,0,stream>>>(W2, W2t, F1, F2, R_REL);
  for (int r=0;r<R_REL;r++){
    k_gemm<false><<<dim3(F2/128, GM),256,0,stream>>>(h1, W2t + (size_t)r*F1*F2,
                                                     xp, nullptr, N_NODES, F1, F2);
    k_al2w<<<N_NODES/4,256,0,stream>>>(xp, a_s2 + (size_t)r*F2, a_d2 + (size_t)r*F2, alS, alD);
    k_edge2<<<N_NODES,64,0,stream>>>(off + (size_t)r*(N_NODES+1), el + (size_t)r*ETOT,
                                     alS, alD, xp, b2 + (size_t)r*F2, h2);
  }

  // ---- layernorm epilogue (f32 output)
  k_final<<<N_NODES,256,0,stream>>>(h2, res_b, ln_g, ln_b, out);
}